// Round 2
// baseline (872.818 us; speedup 1.0000x reference)
//
#include <hip/hip_runtime.h>
#include <stdint.h>

#define H 16
#define SEQ 2048
#define DMODEL 1024
#define DK 64

typedef __attribute__((ext_vector_type(8))) short bf16x8;
typedef __attribute__((ext_vector_type(4))) float f32x4;
typedef __attribute__((ext_vector_type(4))) short s16x4;

__device__ __forceinline__ short f2bf(float f) {
  unsigned u = __float_as_uint(f);
  u += 0x7fffu + ((u >> 16) & 1u);
  return (short)(u >> 16);
}

__device__ __forceinline__ f32x4 mfma16(bf16x8 a, bf16x8 b, f32x4 c) {
  return __builtin_amdgcn_mfma_f32_16x16x32_bf16(a, b, c, 0, 0, 0);
}

// ---------------- cast fp32 -> bf16 (vectorized x4) ----------------
__global__ void cast_bf16_kernel(const float* __restrict__ src,
                                 short* __restrict__ dst, int n4) {
  int i = blockIdx.x * blockDim.x + threadIdx.x;
  if (i < n4) {
    const float4 v = ((const float4*)src)[i];
    s16x4 o;
    o[0] = f2bf(v.x); o[1] = f2bf(v.y); o[2] = f2bf(v.z); o[3] = f2bf(v.w);
    ((s16x4*)dst)[i] = o;
  }
}

// ---------------- NT GEMM, K=1024, 128x128 tile, 4 waves ----------------
// A: [M x 1024] bf16 row-major; Bm: [N x 1024] bf16 row-major (i.e. B^T input).
// out[m][n] = sum_k A[m][k]*Bm[n][k] + bias
// EPI 0: bf16 store to [B,H,S,DK] (row=token, col=feature), bias[col]
// EPI 1: bf16 store to [B,H,DK,S] (row=feature, col=token), bias[row]  (V^T)
// EPI 2: fp32 store to d_out [row*1024+col], bias[col]
template <int EPI>
__global__ __launch_bounds__(256, 2) void gemm_nt(const short* __restrict__ A,
                                                  const short* __restrict__ Bm,
                                                  const float* __restrict__ bias,
                                                  void* __restrict__ outp) {
  __shared__ short Asub[128 * 32];
  __shared__ short Bsub[128 * 32];
  const int tid = threadIdx.x;
  const int lane = tid & 63, wid = tid >> 6;
  const int g = lane >> 4, ln = lane & 15;
  const int wr = wid >> 1, wc = wid & 1;
  const int m0 = blockIdx.y * 128, n0 = blockIdx.x * 128;

  f32x4 acc[4][4] = {};
  const int f0 = tid, f1 = tid + 256;  // staging chunk ids (row=f>>2, c=f&3)

  for (int kt = 0; kt < 32; ++kt) {
    const int k0 = kt * 32;
    bf16x8 a0 = *(const bf16x8*)(A + (size_t)(m0 + (f0 >> 2)) * 1024 + k0 + (f0 & 3) * 8);
    bf16x8 a1 = *(const bf16x8*)(A + (size_t)(m0 + (f1 >> 2)) * 1024 + k0 + (f1 & 3) * 8);
    bf16x8 b0 = *(const bf16x8*)(Bm + (size_t)(n0 + (f0 >> 2)) * 1024 + k0 + (f0 & 3) * 8);
    bf16x8 b1 = *(const bf16x8*)(Bm + (size_t)(n0 + (f1 >> 2)) * 1024 + k0 + (f1 & 3) * 8);
    __syncthreads();  // previous iter's readers done before overwrite
    *(bf16x8*)(Asub + f0 * 8) = a0;
    *(bf16x8*)(Asub + f1 * 8) = a1;
    *(bf16x8*)(Bsub + f0 * 8) = b0;
    *(bf16x8*)(Bsub + f1 * 8) = b1;
    __syncthreads();
    bf16x8 af[4], bfr[4];
#pragma unroll
    for (int mi = 0; mi < 4; ++mi)
      af[mi] = *(const bf16x8*)(Asub + (wr * 64 + mi * 16 + ln) * 32 + 8 * g);
#pragma unroll
    for (int ni = 0; ni < 4; ++ni)
      bfr[ni] = *(const bf16x8*)(Bsub + (wc * 64 + ni * 16 + ln) * 32 + 8 * g);
#pragma unroll
    for (int mi = 0; mi < 4; ++mi)
#pragma unroll
      for (int ni = 0; ni < 4; ++ni)
        acc[mi][ni] = mfma16(af[mi], bfr[ni], acc[mi][ni]);
  }

  // epilogue: D frag row = 4*g + r, col = ln
#pragma unroll
  for (int mi = 0; mi < 4; ++mi) {
#pragma unroll
    for (int r = 0; r < 4; ++r) {
      const int row = m0 + wr * 64 + mi * 16 + 4 * g + r;
#pragma unroll
      for (int ni = 0; ni < 4; ++ni) {
        const int col = n0 + wc * 64 + ni * 16 + ln;
        float vv = acc[mi][ni][r];
        if (EPI == 0) {
          vv += bias[col];
          short* dst = (short*)outp;
          const int bb = row >> 11, s = row & 2047, hh = col >> 6, dk = col & 63;
          dst[(size_t)(bb * H + hh) * SEQ * DK + (size_t)s * DK + dk] = f2bf(vv);
        } else if (EPI == 1) {
          vv += bias[row];
          short* dst = (short*)outp;
          const int hh = row >> 6, dk = row & 63, bb = col >> 11, s = col & 2047;
          dst[(size_t)((bb * H + hh) * DK + dk) * SEQ + s] = f2bf(vv);
        } else {
          vv += bias[col];
          ((float*)outp)[(size_t)row * DMODEL + col] = vv;
        }
      }
    }
  }
}

// ---------------- fused attention ----------------
// grid (S/32, H, B), block 512 (8 waves). Wave w owns j in [w*256, w*256+256).
// Full 32x2048 score tile in registers (acc[2][16] f32x4 per lane).
__global__ __launch_bounds__(512, 2) void attn_fused(const short* __restrict__ qh,
                                                     const short* __restrict__ kh,
                                                     const short* __restrict__ vhT,
                                                     float* __restrict__ attn,
                                                     short* __restrict__ oh) {
  __shared__ short p_scr[8][32][40];     // per-wave P transpose scratch (+pad)
  __shared__ float red_max[32][8];
  __shared__ float red_sum[32][8];
  __shared__ float out_red[8][32][68];   // per-wave PV partials (+pad)

  const int tid = threadIdx.x;
  const int w = tid >> 6, lane = tid & 63, g = lane >> 4, ln = lane & 15;
  const int qt = blockIdx.x, hh = blockIdx.y, b = blockIdx.z, bh = b * H + hh;
  const short* Q = qh + (size_t)bh * SEQ * DK;
  const short* K = kh + (size_t)bh * SEQ * DK;
  const short* VT = vhT + (size_t)bh * DK * SEQ;
  float* attn_b = attn + (size_t)bh * SEQ * SEQ;
  const int q0 = qt * 32, jw = w * 256;

  // Q fragments: A[row=q][k=dk], lane holds row (ln), k = kk*32 + 8g..+8
  bf16x8 aq[2][2];
#pragma unroll
  for (int mi = 0; mi < 2; ++mi)
#pragma unroll
    for (int kk = 0; kk < 2; ++kk)
      aq[mi][kk] = *(const bf16x8*)(Q + (size_t)(q0 + mi * 16 + ln) * DK + kk * 32 + 8 * g);

  // ---- QK^T ----
  f32x4 acc[2][16] = {};
#pragma unroll
  for (int jt = 0; jt < 16; ++jt) {
    bf16x8 bk0 = *(const bf16x8*)(K + (size_t)(jw + jt * 16 + ln) * DK + 8 * g);
    bf16x8 bk1 = *(const bf16x8*)(K + (size_t)(jw + jt * 16 + ln) * DK + 32 + 8 * g);
#pragma unroll
    for (int mi = 0; mi < 2; ++mi) {
      acc[mi][jt] = mfma16(aq[mi][0], bk0, acc[mi][jt]);
      acc[mi][jt] = mfma16(aq[mi][1], bk1, acc[mi][jt]);
    }
  }

  // ---- softmax (scale applied inside exp arg; max subtraction in raw units) ----
  const float sc = 0.125f;  // 1/sqrt(64)
  float M[2][4], L[2][4];
#pragma unroll
  for (int mi = 0; mi < 2; ++mi)
#pragma unroll
    for (int r = 0; r < 4; ++r) {
      float m = acc[mi][0][r];
#pragma unroll
      for (int jt = 1; jt < 16; ++jt) m = fmaxf(m, acc[mi][jt][r]);
#pragma unroll
      for (int msk = 1; msk <= 8; msk <<= 1) m = fmaxf(m, __shfl_xor(m, msk));
      M[mi][r] = m;
    }
  if (ln == 0) {
#pragma unroll
    for (int mi = 0; mi < 2; ++mi)
#pragma unroll
      for (int r = 0; r < 4; ++r) red_max[mi * 16 + 4 * g + r][w] = M[mi][r];
  }
  __syncthreads();
#pragma unroll
  for (int mi = 0; mi < 2; ++mi)
#pragma unroll
    for (int r = 0; r < 4; ++r) {
      float m = red_max[mi * 16 + 4 * g + r][0];
#pragma unroll
      for (int ww = 1; ww < 8; ++ww) m = fmaxf(m, red_max[mi * 16 + 4 * g + r][ww]);
      M[mi][r] = m;
    }
#pragma unroll
  for (int mi = 0; mi < 2; ++mi)
#pragma unroll
    for (int r = 0; r < 4; ++r) {
      float ssum = 0.f;
#pragma unroll
      for (int jt = 0; jt < 16; ++jt) {
        float p = __expf((acc[mi][jt][r] - M[mi][r]) * sc);
        acc[mi][jt][r] = p;
        ssum += p;
      }
#pragma unroll
      for (int msk = 1; msk <= 8; msk <<= 1) ssum += __shfl_xor(ssum, msk);
      L[mi][r] = ssum;
    }
  if (ln == 0) {
#pragma unroll
    for (int mi = 0; mi < 2; ++mi)
#pragma unroll
      for (int r = 0; r < 4; ++r) red_sum[mi * 16 + 4 * g + r][w] = L[mi][r];
  }
  __syncthreads();
  float inv[2][4];
#pragma unroll
  for (int mi = 0; mi < 2; ++mi)
#pragma unroll
    for (int r = 0; r < 4; ++r) {
      float ssum = red_sum[mi * 16 + 4 * g + r][0];
#pragma unroll
      for (int ww = 1; ww < 8; ++ww) ssum += red_sum[mi * 16 + 4 * g + r][ww];
      inv[mi][r] = 1.0f / ssum;
    }

  // ---- attn store + PV (per-wave over its 256-j slice) ----
  f32x4 opv[2][4] = {};
#pragma unroll
  for (int jt2 = 0; jt2 < 8; ++jt2) {
#pragma unroll
    for (int half = 0; half < 2; ++half) {
      const int jt = jt2 * 2 + half;
#pragma unroll
      for (int mi = 0; mi < 2; ++mi)
#pragma unroll
        for (int r = 0; r < 4; ++r) {
          const float p = acc[mi][jt][r] * inv[mi][r];
          const int qrow = mi * 16 + 4 * g + r;
          attn_b[(size_t)(q0 + qrow) * SEQ + jw + jt * 16 + ln] = p;
          p_scr[w][qrow][half * 16 + ln] = f2bf(p);
        }
    }
    // wave-local LDS visibility (cross-lane write->read within wave)
    __asm__ volatile("s_waitcnt lgkmcnt(0)" ::: "memory");
    __builtin_amdgcn_sched_barrier(0);
    bf16x8 pa[2];
#pragma unroll
    for (int mi = 0; mi < 2; ++mi)
      pa[mi] = *(const bf16x8*)(&p_scr[w][mi * 16 + ln][8 * g]);
#pragma unroll
    for (int di = 0; di < 4; ++di) {
      bf16x8 bv = *(const bf16x8*)(VT + (size_t)(di * 16 + ln) * SEQ + jw + jt2 * 32 + 8 * g);
#pragma unroll
      for (int mi = 0; mi < 2; ++mi) opv[mi][di] = mfma16(pa[mi], bv, opv[mi][di]);
    }
  }

  // ---- cross-wave reduce of PV partials, store merged out_h (bf16) ----
#pragma unroll
  for (int mi = 0; mi < 2; ++mi)
#pragma unroll
    for (int di = 0; di < 4; ++di)
#pragma unroll
      for (int r = 0; r < 4; ++r)
        out_red[w][mi * 16 + 4 * g + r][di * 16 + ln] = opv[mi][di][r];
  __syncthreads();
  const int e0 = tid * 4, qq = e0 >> 6, dd = e0 & 63;
  s16x4 ov;
#pragma unroll
  for (int e = 0; e < 4; ++e) {
    float s = 0.f;
#pragma unroll
    for (int ww = 0; ww < 8; ++ww) s += out_red[ww][qq][dd + e];
    ov[e] = f2bf(s);
  }
  *(s16x4*)(oh + (size_t)(b * SEQ + q0 + qq) * DMODEL + hh * DK + dd) = ov;
}

// ---------------- launcher ----------------
extern "C" void kernel_launch(void* const* d_in, const int* in_sizes, int n_in,
                              void* d_out, int out_size, void* d_ws, size_t ws_size,
                              hipStream_t stream) {
  (void)in_sizes; (void)n_in; (void)out_size; (void)ws_size;
  const float* q  = (const float*)d_in[0];
  const float* k  = (const float*)d_in[1];
  const float* v  = (const float*)d_in[2];
  const float* wq = (const float*)d_in[3];
  const float* bq = (const float*)d_in[4];
  const float* wk = (const float*)d_in[5];
  const float* bk = (const float*)d_in[6];
  const float* wv = (const float*)d_in[7];
  const float* bv = (const float*)d_in[8];
  const float* wo = (const float*)d_in[9];
  const float* bo = (const float*)d_in[10];

  const size_t NTOK = (size_t)4096 * 1024;  // 4,194,304
  const size_t NW = (size_t)1024 * 1024;
  short* ws = (short*)d_ws;
  short* xq  = ws;
  short* xk  = xq + NTOK;
  short* xv  = xk + NTOK;
  short* wqb = xv + NTOK;
  short* wkb = wqb + NW;
  short* wvb = wkb + NW;
  short* wob = wvb + NW;
  short* qhb = wob + NW;
  short* khb = qhb + NTOK;
  short* vtb = khb + NTOK;   // V^T: [B,H,DK,S]
  short* ohb = vtb + NTOK;   // merged attention output [B,S,D] bf16

  float* outp  = (float*)d_out;
  float* attnp = outp + NTOK;  // attn region: [B,H,S,S] fp32

  cast_bf16_kernel<<<4096, 256, 0, stream>>>(q, xq, (int)(NTOK / 4));
  cast_bf16_kernel<<<4096, 256, 0, stream>>>(k, xk, (int)(NTOK / 4));
  cast_bf16_kernel<<<4096, 256, 0, stream>>>(v, xv, (int)(NTOK / 4));
  cast_bf16_kernel<<<1024, 256, 0, stream>>>(wq, wqb, (int)(NW / 4));
  cast_bf16_kernel<<<1024, 256, 0, stream>>>(wk, wkb, (int)(NW / 4));
  cast_bf16_kernel<<<1024, 256, 0, stream>>>(wv, wvb, (int)(NW / 4));
  cast_bf16_kernel<<<1024, 256, 0, stream>>>(wo, wob, (int)(NW / 4));

  // Q/K projections: M=4096 tokens, N=1024 features
  gemm_nt<0><<<dim3(8, 32), 256, 0, stream>>>(xq, wqb, bq, qhb);
  gemm_nt<0><<<dim3(8, 32), 256, 0, stream>>>(xk, wkb, bk, khb);
  // V projection transposed: out[n_feat][token] = Wv . X^T  -> [B,H,DK,S]
  gemm_nt<1><<<dim3(32, 8), 256, 0, stream>>>(wvb, xv, bv, vtb);

  attn_fused<<<dim3(SEQ / 32, H, 2), 512, 0, stream>>>(qhb, khb, vtb, attnp, ohb);

  // output projection: fp32 + bias into d_out
  gemm_nt<2><<<dim3(8, 32), 256, 0, stream>>>(ohb, wob, bo, outp);
}

// Round 3
// 844.191 us; speedup vs baseline: 1.0339x; 1.0339x over previous
//
#include <hip/hip_runtime.h>
#include <stdint.h>

#define H 16
#define SEQ 2048
#define DMODEL 1024
#define DK 64

typedef __attribute__((ext_vector_type(8))) short bf16x8;
typedef __attribute__((ext_vector_type(4))) float f32x4;
typedef __attribute__((ext_vector_type(4))) short s16x4;

__device__ __forceinline__ short f2bf(float f) {
  unsigned u = __float_as_uint(f);
  u += 0x7fffu + ((u >> 16) & 1u);
  return (short)(u >> 16);
}

__device__ __forceinline__ f32x4 mfma16(bf16x8 a, bf16x8 b, f32x4 c) {
  return __builtin_amdgcn_mfma_f32_16x16x32_bf16(a, b, c, 0, 0, 0);
}

// async global->LDS, 16B per lane; lds base must be wave-uniform
__device__ __forceinline__ void gload16(short* lds, const short* g) {
  __builtin_amdgcn_global_load_lds(
      (const __attribute__((address_space(1))) unsigned int*)g,
      (__attribute__((address_space(3))) unsigned int*)lds, 16, 0, 0);
}

// ---------------- fused cast fp32 -> bf16 (all 7 arrays, one launch) ----------------
__global__ void cast_all(const float* __restrict__ q, const float* __restrict__ k,
                         const float* __restrict__ v, const float* __restrict__ wq,
                         const float* __restrict__ wk, const float* __restrict__ wv,
                         const float* __restrict__ wo, short* __restrict__ xq,
                         short* __restrict__ xk, short* __restrict__ xv,
                         short* __restrict__ wqb, short* __restrict__ wkb,
                         short* __restrict__ wvb, short* __restrict__ wob) {
  const int bid = blockIdx.x;
  const float* src;
  short* dst;
  int base;
  if (bid < 4096) { src = q; dst = xq; base = bid; }
  else if (bid < 8192) { src = k; dst = xk; base = bid - 4096; }
  else if (bid < 12288) { src = v; dst = xv; base = bid - 8192; }
  else if (bid < 13312) { src = wq; dst = wqb; base = bid - 12288; }
  else if (bid < 14336) { src = wk; dst = wkb; base = bid - 13312; }
  else if (bid < 15360) { src = wv; dst = wvb; base = bid - 14336; }
  else { src = wo; dst = wob; base = bid - 15360; }
  const int i = base * 256 + threadIdx.x;
  const float4 val = ((const float4*)src)[i];
  s16x4 o;
  o[0] = f2bf(val.x); o[1] = f2bf(val.y); o[2] = f2bf(val.z); o[3] = f2bf(val.w);
  ((s16x4*)dst)[i] = o;
}

// ---------------- NT GEMM body, K=1024, 128x128 tile, 4 waves, gload_lds ----------------
// A: [M x 1024] bf16 row-major; Bm: [N x 1024] bf16 row-major (B^T input).
// out[m][n] = sum_k A[m][k]*Bm[n][k] + bias
// EPI 0: bf16 store [B,H,S,DK] (row=token,col=feature), bias[col]
// EPI 1: bf16 store [B,H,DK,S] (row=feature,col=token), bias[row]  (V^T)
// EPI 2: fp32 store d_out [row*1024+col], bias[col]
template <int EPI>
__device__ __forceinline__ void gemm_body(const short* __restrict__ A,
                                          const short* __restrict__ Bm,
                                          const float* __restrict__ bias,
                                          void* __restrict__ outp,
                                          const int m0, const int n0) {
  __shared__ short Asub[128 * 32];
  __shared__ short Bsub[128 * 32];
  const int tid = threadIdx.x;
  const int lane = tid & 63, wid = tid >> 6;
  const int g = lane >> 4, ln = lane & 15;
  const int wr = wid >> 1, wc = wid & 1;

  f32x4 acc[4][4] = {};
  const int f0 = tid, f1 = tid + 256;
  const int r0 = f0 >> 2, c0 = (f0 & 3) * 8;
  const int r1 = f1 >> 2, c1 = (f1 & 3) * 8;
  short* lb0a = Asub + (wid * 64) * 8;
  short* lb1a = Asub + (256 + wid * 64) * 8;
  short* lb0b = Bsub + (wid * 64) * 8;
  short* lb1b = Bsub + (256 + wid * 64) * 8;

  for (int kt = 0; kt < 32; ++kt) {
    const int k0 = kt * 32;
    __syncthreads();  // prior iter's LDS readers done
    gload16(lb0a, A + (size_t)(m0 + r0) * 1024 + k0 + c0);
    gload16(lb1a, A + (size_t)(m0 + r1) * 1024 + k0 + c1);
    gload16(lb0b, Bm + (size_t)(n0 + r0) * 1024 + k0 + c0);
    gload16(lb1b, Bm + (size_t)(n0 + r1) * 1024 + k0 + c1);
    __syncthreads();  // drains vmcnt -> staged data visible
    bf16x8 af[4], bfr[4];
#pragma unroll
    for (int mi = 0; mi < 4; ++mi)
      af[mi] = *(const bf16x8*)(Asub + (wr * 64 + mi * 16 + ln) * 32 + 8 * g);
#pragma unroll
    for (int ni = 0; ni < 4; ++ni)
      bfr[ni] = *(const bf16x8*)(Bsub + (wc * 64 + ni * 16 + ln) * 32 + 8 * g);
#pragma unroll
    for (int mi = 0; mi < 4; ++mi)
#pragma unroll
      for (int ni = 0; ni < 4; ++ni)
        acc[mi][ni] = mfma16(af[mi], bfr[ni], acc[mi][ni]);
  }

#pragma unroll
  for (int mi = 0; mi < 4; ++mi) {
#pragma unroll
    for (int r = 0; r < 4; ++r) {
      const int row = m0 + wr * 64 + mi * 16 + 4 * g + r;
#pragma unroll
      for (int ni = 0; ni < 4; ++ni) {
        const int col = n0 + wc * 64 + ni * 16 + ln;
        float vv = acc[mi][ni][r];
        if (EPI == 0) {
          vv += bias[col];
          short* dst = (short*)outp;
          const int bb = row >> 11, s = row & 2047, hh = col >> 6, dk = col & 63;
          dst[(size_t)(bb * H + hh) * SEQ * DK + (size_t)s * DK + dk] = f2bf(vv);
        } else if (EPI == 1) {
          vv += bias[row];
          short* dst = (short*)outp;
          const int hh = row >> 6, dk = row & 63, bb = col >> 11, s = col & 2047;
          dst[(size_t)((bb * H + hh) * DK + dk) * SEQ + s] = f2bf(vv);
        } else {
          vv += bias[col];
          ((float*)outp)[(size_t)row * DMODEL + col] = vv;
        }
      }
    }
  }
}

// Q + K projections batched (seg = blockIdx.x>>3) for 2 blocks/CU occupancy
__global__ __launch_bounds__(256, 2) void gemm_qk(const short* __restrict__ xq,
                                                  const short* __restrict__ xk,
                                                  const short* __restrict__ wqb,
                                                  const short* __restrict__ wkb,
                                                  const float* __restrict__ bq,
                                                  const float* __restrict__ bk,
                                                  short* __restrict__ qhb,
                                                  short* __restrict__ khb) {
  const int seg = blockIdx.x >> 3;
  const int n0 = (blockIdx.x & 7) * 128;
  const int m0 = blockIdx.y * 128;
  gemm_body<0>(seg ? xk : xq, seg ? wkb : wqb, seg ? bk : bq,
               seg ? (void*)khb : (void*)qhb, m0, n0);
}

template <int EPI>
__global__ __launch_bounds__(256, 2) void gemm_nt(const short* __restrict__ A,
                                                  const short* __restrict__ Bm,
                                                  const float* __restrict__ bias,
                                                  void* __restrict__ outp) {
  gemm_body<EPI>(A, Bm, bias, outp, blockIdx.y * 128, blockIdx.x * 128);
}

// ---------------- fused attention, 3-pass (max / denom / store+PV) ----------------
// grid 2048 (1D, XCD-swizzled), block 512 (8 waves). Wave w owns j in [w*256, w*256+256).
__global__ __launch_bounds__(512, 4) void attn_fused(const short* __restrict__ qh,
                                                     const short* __restrict__ kh,
                                                     const short* __restrict__ vhT,
                                                     float* __restrict__ attn,
                                                     short* __restrict__ oh) {
  __shared__ __align__(16) char smem[8 * 32 * 68 * 4];  // union: p_scr | out_red
  __shared__ float red_mx[32][8];
  __shared__ float red_sm[32][8];
  short (*p_scr)[32][40] = (short (*)[32][40])smem;
  float (*out_red)[32][68] = (float (*)[32][68])smem;

  const int tid = threadIdx.x;
  const int w = tid >> 6, lane = tid & 63, g = lane >> 4, ln = lane & 15;
  int wg = (int)blockIdx.x;
  wg = (wg & 7) * 256 + (wg >> 3);  // bijective XCD chunk swizzle (2048 % 8 == 0)
  const int qt = wg & 63, hh = (wg >> 6) & 15, b = wg >> 10;
  const int bh = b * H + hh;
  const short* Q = qh + (size_t)bh * SEQ * DK;
  const short* K = kh + (size_t)bh * SEQ * DK;
  const short* VT = vhT + (size_t)bh * DK * SEQ;
  float* attn_b = attn + (size_t)bh * SEQ * SEQ;
  const int q0 = qt * 32, jw = w * 256;
  const float c = 0.18033688f;  // (1/sqrt(64)) * log2(e)

  // Q fragments (persistent): A[row=q][k=dk]
  bf16x8 aq[2][2];
#pragma unroll
  for (int mi = 0; mi < 2; ++mi)
#pragma unroll
    for (int kk = 0; kk < 2; ++kk)
      aq[mi][kk] = *(const bf16x8*)(Q + (size_t)(q0 + mi * 16 + ln) * DK + kk * 32 + 8 * g);

  // ---- pass A: row max ----
  float mx[2][4];
#pragma unroll
  for (int mi = 0; mi < 2; ++mi)
#pragma unroll
    for (int r = 0; r < 4; ++r) mx[mi][r] = -3.0e38f;
  for (int jt = 0; jt < 16; ++jt) {
    bf16x8 bk0 = *(const bf16x8*)(K + (size_t)(jw + jt * 16 + ln) * DK + 8 * g);
    bf16x8 bk1 = *(const bf16x8*)(K + (size_t)(jw + jt * 16 + ln) * DK + 32 + 8 * g);
    f32x4 a0 = {}, a1 = {};
    a0 = mfma16(aq[0][0], bk0, a0);
    a0 = mfma16(aq[0][1], bk1, a0);
    a1 = mfma16(aq[1][0], bk0, a1);
    a1 = mfma16(aq[1][1], bk1, a1);
#pragma unroll
    for (int r = 0; r < 4; ++r) {
      mx[0][r] = fmaxf(mx[0][r], a0[r]);
      mx[1][r] = fmaxf(mx[1][r], a1[r]);
    }
  }
#pragma unroll
  for (int msk = 1; msk <= 8; msk <<= 1)
#pragma unroll
    for (int mi = 0; mi < 2; ++mi)
#pragma unroll
      for (int r = 0; r < 4; ++r) mx[mi][r] = fmaxf(mx[mi][r], __shfl_xor(mx[mi][r], msk));
  if (ln == 0) {
#pragma unroll
    for (int mi = 0; mi < 2; ++mi)
#pragma unroll
      for (int r = 0; r < 4; ++r) red_mx[mi * 16 + 4 * g + r][w] = mx[mi][r];
  }
  __syncthreads();
  float M[2][4];
#pragma unroll
  for (int mi = 0; mi < 2; ++mi)
#pragma unroll
    for (int r = 0; r < 4; ++r) {
      float m = red_mx[mi * 16 + 4 * g + r][0];
#pragma unroll
      for (int ww = 1; ww < 8; ++ww) m = fmaxf(m, red_mx[mi * 16 + 4 * g + r][ww]);
      M[mi][r] = m;
    }

  // ---- pass B: denom ----
  float sm[2][4] = {};
  for (int jt = 0; jt < 16; ++jt) {
    bf16x8 bk0 = *(const bf16x8*)(K + (size_t)(jw + jt * 16 + ln) * DK + 8 * g);
    bf16x8 bk1 = *(const bf16x8*)(K + (size_t)(jw + jt * 16 + ln) * DK + 32 + 8 * g);
    f32x4 a0 = {}, a1 = {};
    a0 = mfma16(aq[0][0], bk0, a0);
    a0 = mfma16(aq[0][1], bk1, a0);
    a1 = mfma16(aq[1][0], bk0, a1);
    a1 = mfma16(aq[1][1], bk1, a1);
#pragma unroll
    for (int r = 0; r < 4; ++r) {
      sm[0][r] += exp2f((a0[r] - M[0][r]) * c);
      sm[1][r] += exp2f((a1[r] - M[1][r]) * c);
    }
  }
#pragma unroll
  for (int msk = 1; msk <= 8; msk <<= 1)
#pragma unroll
    for (int mi = 0; mi < 2; ++mi)
#pragma unroll
      for (int r = 0; r < 4; ++r) sm[mi][r] += __shfl_xor(sm[mi][r], msk);
  if (ln == 0) {
#pragma unroll
    for (int mi = 0; mi < 2; ++mi)
#pragma unroll
      for (int r = 0; r < 4; ++r) red_sm[mi * 16 + 4 * g + r][w] = sm[mi][r];
  }
  __syncthreads();
  float inv[2][4];
#pragma unroll
  for (int mi = 0; mi < 2; ++mi)
#pragma unroll
    for (int r = 0; r < 4; ++r) {
      float s = red_sm[mi * 16 + 4 * g + r][0];
#pragma unroll
      for (int ww = 1; ww < 8; ++ww) s += red_sm[mi * 16 + 4 * g + r][ww];
      inv[mi][r] = 1.0f / s;
    }

  // ---- pass C: normalize + store attn (nontemporal) + PV ----
  f32x4 opv[2][4] = {};
  for (int jt2 = 0; jt2 < 8; ++jt2) {
#pragma unroll
    for (int half = 0; half < 2; ++half) {
      const int jt = jt2 * 2 + half;
      bf16x8 bk0 = *(const bf16x8*)(K + (size_t)(jw + jt * 16 + ln) * DK + 8 * g);
      bf16x8 bk1 = *(const bf16x8*)(K + (size_t)(jw + jt * 16 + ln) * DK + 32 + 8 * g);
      f32x4 a0 = {}, a1 = {};
      a0 = mfma16(aq[0][0], bk0, a0);
      a0 = mfma16(aq[0][1], bk1, a0);
      a1 = mfma16(aq[1][0], bk0, a1);
      a1 = mfma16(aq[1][1], bk1, a1);
#pragma unroll
      for (int mi = 0; mi < 2; ++mi)
#pragma unroll
        for (int r = 0; r < 4; ++r) {
          const float v = (mi == 0) ? a0[r] : a1[r];
          const float p = exp2f((v - M[mi][r]) * c) * inv[mi][r];
          const int qrow = mi * 16 + 4 * g + r;
          __builtin_nontemporal_store(p, &attn_b[(size_t)(q0 + qrow) * SEQ + jw + jt * 16 + ln]);
          p_scr[w][qrow][half * 16 + ln] = f2bf(p);
        }
    }
    // wave-local LDS visibility (cross-lane write->read within wave)
    __asm__ volatile("s_waitcnt lgkmcnt(0)" ::: "memory");
    __builtin_amdgcn_sched_barrier(0);
    bf16x8 pa[2];
#pragma unroll
    for (int mi = 0; mi < 2; ++mi)
      pa[mi] = *(const bf16x8*)(&p_scr[w][mi * 16 + ln][8 * g]);
#pragma unroll
    for (int di = 0; di < 4; ++di) {
      bf16x8 bv = *(const bf16x8*)(VT + (size_t)(di * 16 + ln) * SEQ + jw + jt2 * 32 + 8 * g);
      opv[0][di] = mfma16(pa[0], bv, opv[0][di]);
      opv[1][di] = mfma16(pa[1], bv, opv[1][di]);
    }
  }

  // ---- cross-wave reduce of PV partials (out_red aliases p_scr: barrier first) ----
  __syncthreads();
#pragma unroll
  for (int mi = 0; mi < 2; ++mi)
#pragma unroll
    for (int di = 0; di < 4; ++di)
#pragma unroll
      for (int r = 0; r < 4; ++r)
        out_red[w][mi * 16 + 4 * g + r][di * 16 + ln] = opv[mi][di][r];
  __syncthreads();
  const int e0 = tid * 4, qq = e0 >> 6, dd = e0 & 63;
  s16x4 ov;
#pragma unroll
  for (int e = 0; e < 4; ++e) {
    float s = 0.f;
#pragma unroll
    for (int ww = 0; ww < 8; ++ww) s += out_red[ww][qq][dd + e];
    ov[e] = f2bf(s);
  }
  *(s16x4*)(oh + (size_t)(b * SEQ + q0 + qq) * DMODEL + hh * DK + dd) = ov;
}

// ---------------- launcher ----------------
extern "C" void kernel_launch(void* const* d_in, const int* in_sizes, int n_in,
                              void* d_out, int out_size, void* d_ws, size_t ws_size,
                              hipStream_t stream) {
  (void)in_sizes; (void)n_in; (void)out_size; (void)ws_size;
  const float* q  = (const float*)d_in[0];
  const float* k  = (const float*)d_in[1];
  const float* v  = (const float*)d_in[2];
  const float* wq = (const float*)d_in[3];
  const float* bq = (const float*)d_in[4];
  const float* wk = (const float*)d_in[5];
  const float* bk = (const float*)d_in[6];
  const float* wv = (const float*)d_in[7];
  const float* bv = (const float*)d_in[8];
  const float* wo = (const float*)d_in[9];
  const float* bo = (const float*)d_in[10];

  const size_t NTOK = (size_t)4096 * 1024;
  const size_t NW = (size_t)1024 * 1024;
  short* ws = (short*)d_ws;
  short* xq  = ws;
  short* xk  = xq + NTOK;
  short* xv  = xk + NTOK;
  short* wqb = xv + NTOK;
  short* wkb = wqb + NW;
  short* wvb = wkb + NW;
  short* wob = wvb + NW;
  short* qhb = wob + NW;
  short* khb = qhb + NTOK;
  short* vtb = khb + NTOK;   // V^T: [B,H,DK,S]
  short* ohb = vtb + NTOK;   // merged attention output [B,S,D] bf16

  float* outp  = (float*)d_out;
  float* attnp = outp + NTOK;  // attn region: [B,H,S,S] fp32

  cast_all<<<16384, 256, 0, stream>>>(q, k, v, wq, wk, wv, wo,
                                      xq, xk, xv, wqb, wkb, wvb, wob);

  // Q+K projections batched: x = seg*8 + ntile
  gemm_qk<<<dim3(16, 32), 256, 0, stream>>>(xq, xk, wqb, wkb, bq, bk, qhb, khb);
  // V projection transposed: out[feat][token] -> [B,H,DK,S]
  gemm_nt<1><<<dim3(32, 8), 256, 0, stream>>>(wvb, xv, bv, vtb);

  attn_fused<<<2048, 512, 0, stream>>>(qhb, khb, vtb, attnp, ohb);

  // output projection: fp32 + bias into d_out
  gemm_nt<2><<<dim3(8, 32), 256, 0, stream>>>(ohb, wob, bo, outp);
}